// Round 17
// baseline (858.300 us; speedup 1.0000x reference)
//
#include <hip/hip_runtime.h>
#include <hip/hip_bf16.h>
#include <stdint.h>

// ---------------------------------------------------------------------------
// QuantGRU: T=512, B=64, I=256, H=256. ACT scale 2^-7, W scale 2^-8.
// Fully exact integer arithmetic; sigmoid/tanh via 256-entry f64-built LUTs.
// R17: TWO batches per block with K-split. The invariant ~1900 cyc/step wall
// across R3-R16 = 196KB/step weight streaming into the CU (never resident).
// That traffic -- and the serial chain + barriers -- now serve 2 batches:
// thread (kh,j) holds cols {j,j+256,j+512} x K-half (96 dw, R4's footprint),
// computes partials for BOTH batches; integer partials exchanged via LDS
// (exact); gates split: tid<256 batch A, tid>=256 batch B (parallel chains).
// ---------------------------------------------------------------------------

#define T_STEPS 512
#define BATCH   64
#define IDIM    256
#define HDIM    256
#define N3H     768   // 3*H

#if defined(__has_builtin)
#if __has_builtin(__builtin_amdgcn_sdot4)
#define DOT4(a,b,c) __builtin_amdgcn_sdot4((int)(a),(int)(b),(int)(c),false)
#endif
#endif
#ifndef DOT4
__device__ __forceinline__ int dot4_sw(uint32_t a, uint32_t b, int c){
  c += (int)(int8_t)(a)      * (int)(int8_t)(b);
  c += (int)(int8_t)(a>>8)   * (int)(int8_t)(b>>8);
  c += (int)(int8_t)(a>>16)  * (int)(int8_t)(b>>16);
  c += (int)(int8_t)(a>>24)  * (int)(int8_t)(b>>24);
  return c;
}
#define DOT4(a,b,c) dot4_sw((uint32_t)(a),(uint32_t)(b),(int)(c))
#endif

// select dword component of a uint4 by compile-time constant
#define CHUNK(W,c) (((c)&3)==0 ? W[(c)>>2].x : ((c)&3)==1 ? W[(c)>>2].y : \
                    ((c)&3)==2 ? W[(c)>>2].z : W[(c)>>2].w)

// LDS-only workgroup barrier (no vmcnt drain; loads/stores stay in flight)
__device__ __forceinline__ void barrier_lds() {
  asm volatile("s_waitcnt lgkmcnt(0)\n\ts_barrier" ::: "memory");
}

// ---- exact integer round-to-nearest-even helpers (verified vs jnp.round) ---
__device__ __forceinline__ int clamp8(int x)   { return min(127, max(-128, x)); }
__device__ __forceinline__ int rne_half(int y) { int t = y >> 1; return t + (t & y & 1); }
__device__ __forceinline__ int rne_s8(int s)   { return (s + 127 + ((s >> 8) & 1)) >> 8; }
__device__ __forceinline__ int rne_s7(int p)   { return (p + 63 + ((p >> 7) & 1)) >> 7; }

// float RNE+clamp (quantize; used in prep/gemm only)
__device__ __forceinline__ int rneclamp(float v) {
  int q = (int)rintf(v);
  return min(127, max(-128, q));
}

__device__ __forceinline__ uint32_t packq4(float4 f, float sc) {
  uint32_t b0 = (uint32_t)(uint8_t)(int8_t)rneclamp(f.x * sc);
  uint32_t b1 = (uint32_t)(uint8_t)(int8_t)rneclamp(f.y * sc);
  uint32_t b2 = (uint32_t)(uint8_t)(int8_t)rneclamp(f.z * sc);
  uint32_t b3 = (uint32_t)(uint8_t)(int8_t)rneclamp(f.w * sc);
  return b0 | (b1 << 8) | (b2 << 16) | (b3 << 24);
}

// ---------------------------------------------------------------------------
// prep: W -> k-chunk-transposed int8 (for gemm_wx coalesced column loads),
// R -> plain column-major int8, biases -> int8.
// ---------------------------------------------------------------------------
__global__ void prep_kernel(const float* __restrict__ W, const float* __restrict__ R,
                            const float* __restrict__ bx, const float* __restrict__ br,
                            int8_t* __restrict__ Wq, int8_t* __restrict__ Rq,
                            int8_t* __restrict__ bx8, int8_t* __restrict__ br8) {
  const int NW = IDIM * N3H; // 196608
  int idx = blockIdx.x * 256 + threadIdx.x;
  if (idx < NW) {
    int k = idx / N3H, j = idx % N3H;
    Wq[((size_t)(k >> 4) * N3H + j) * 16 + (k & 15)] = (int8_t)rneclamp(W[idx] * 256.0f);
  } else if (idx < 2 * NW) {
    int i2 = idx - NW;
    int k = i2 / N3H, j = i2 % N3H;
    Rq[(size_t)j * HDIM + k] = (int8_t)rneclamp(R[i2] * 256.0f);   // col-major
  } else if (idx < 2 * NW + N3H) {
    int i2 = idx - 2 * NW;
    bx8[i2] = (int8_t)rneclamp(bx[i2] * 256.0f);
  } else if (idx < 2 * NW + 2 * N3H) {
    int i2 = idx - 2 * NW - N3H;
    br8[i2] = (int8_t)rneclamp(br[i2] * 256.0f);
  }
}

// ---------------------------------------------------------------------------
// gemm_wx: Wx_q[b][t][j] = clamp(rne( (fq(x) . Wq col j) / 256 ))  (int8)
// one block per t (64 rows), 768 threads = one per output column.
// ---------------------------------------------------------------------------
__global__ __launch_bounds__(768, 1) void gemm_wx_kernel(
    const float* __restrict__ x, const int8_t* __restrict__ Wq,
    int8_t* __restrict__ WxQ8) {
  const int t = blockIdx.x;   // 0..511
  const int j = threadIdx.x;  // 0..767

  __shared__ uint4 xq4[64 * 16];   // 64 rows x 256 int8 = 16KB
  uint32_t* xq = (uint32_t*)xq4;

  uint4 w[16];
  const uint4* wp = (const uint4*)Wq;
  #pragma unroll
  for (int kk = 0; kk < 16; ++kk) w[kk] = wp[kk * N3H + j];

  const float4* xg = (const float4*)(x) + (size_t)t * 4096;
  for (int i = j; i < 4096; i += 768) {
    float4 f = xg[i];
    xq[i] = packq4(f, 128.0f);
  }
  __syncthreads();

  for (int r = 0; r < 64; ++r) {
    int s = 0;
    #pragma unroll
    for (int kk = 0; kk < 16; ++kk) {
      uint4 hv = xq4[r * 16 + kk];
      s = DOT4(hv.x, w[kk].x, s);
      s = DOT4(hv.y, w[kk].y, s);
      s = DOT4(hv.z, w[kk].z, s);
      s = DOT4(hv.w, w[kk].w, s);
    }
    int q = clamp8(rne_s8(s));
    WxQ8[((size_t)r * T_STEPS + t) * N3H + j] = (int8_t)q;
  }
}

// ---------------------------------------------------------------------------
// gru_rec17: one block per PAIR of batches; 512 threads = 8 waves.
// Thread (kh=tid>>8, j=tid&255): cols {j,j+256,j+512} x K-half kh (96 dw),
// partial dots for BOTH batches. kh=1 publishes A-partials, kh=0 publishes
// B-partials (LDS, integer-exact). Gates: tid<256 batch A, tid>=256 batch B.
// ---------------------------------------------------------------------------
__global__ __launch_bounds__(512, 1)
void gru_rec17_kernel(
    const float* __restrict__ h0, const int8_t* __restrict__ Rq,
    const int8_t* __restrict__ bx8, const int8_t* __restrict__ br8,
    const int8_t* __restrict__ WxQ8, float* __restrict__ out) {
  const int bA = blockIdx.x * 2;
  const int bB = bA + 1;
  const int tid = threadIdx.x;    // 0..511
  const int kh  = tid >> 8;       // K-half
  const int j   = tid & 255;      // column-triple / h index
  const int lane = tid & 63;

  __shared__ uint32_t hqA[2][64];   // double-buffered int8 h, batch A
  __shared__ uint32_t hqB[2][64];   // batch B
  __shared__ int pubA[3][256];      // kh=1's partials of batch A
  __shared__ int pubB[3][256];      // kh=0's partials of batch B
  __shared__ int8_t lutS[256];
  __shared__ int8_t lutT[256];

  // weights: 3 cols x own K-half = 24 uint4 (96 dwords)
  uint4 wz[8], wr[8], wg[8];
  {
    const uint4* pz = (const uint4*)(Rq + (size_t)j * HDIM)         + kh * 8;
    const uint4* pr = (const uint4*)(Rq + (size_t)(j + 256) * HDIM) + kh * 8;
    const uint4* pg = (const uint4*)(Rq + (size_t)(j + 512) * HDIM) + kh * 8;
    #pragma unroll
    for (int kk = 0; kk < 8; ++kk) { wz[kk] = pz[kk]; wr[kk] = pr[kk]; wg[kk] = pg[kk]; }
  }
  // gate state: this thread's own batch (A if kh==0 else B), column j
  const int myb = kh ? bB : bA;
  const int bzc = (int)bx8[j];
  const int brc = (int)bx8[j + 256];
  const int bgc = (int)bx8[j + 512];
  const int vbz = (int)br8[j];
  const int vbr = (int)br8[j + 256];
  const int vbg = (int)br8[j + 512];

  if (tid < 256) {
    double a = ((double)j - 128.0) / 128.0;
    lutS[j] = (int8_t)min(127, max(-128, (int)rint(128.0 / (1.0 + exp(-a)))));
    lutT[j] = (int8_t)min(127, max(-128, (int)rint(128.0 * tanh(a))));
    int hA0 = (int)rintf(h0[bA * HDIM + j] * 128.0f);
    int hB0 = (int)rintf(h0[bB * HDIM + j] * 128.0f);
    ((int8_t*)&hqA[0][0])[j] = (int8_t)clamp8(hA0);
    ((int8_t*)&hqB[0][0])[j] = (int8_t)clamp8(hB0);
  }
  int hi = (int)rintf(h0[myb * HDIM + j] * 128.0f);   // exact int, units 1/128

  const int8_t* wxp = WxQ8 + (size_t)myb * T_STEPS * N3H + j;
  float* outp = out + (size_t)myb * HDIM + j;
  // 2-deep Wx prefetch
  int wxA0 = (int)wxp[0],   wxA1 = (int)wxp[256],       wxA2 = (int)wxp[512];
  int wxB0 = (int)wxp[N3H], wxB1 = (int)wxp[N3H + 256], wxB2 = (int)wxp[N3H + 512];
  __syncthreads();

  for (int t = 0; t < T_STEPS; ++t) {
    const int cur = t & 1, nxt = cur ^ 1;

    // issue Wx loads for t+2 first
    const int8_t* p = wxp + (size_t)min(t + 2, T_STEPS - 1) * N3H;
    int nz = (int)p[0], nr = (int)p[256], ng = (int)p[512];

    // ---- GEMV partials for BOTH batches over own K-half ----
    uint32_t hwA = hqA[cur][kh * 32 + (lane & 31)];
    uint32_t hwB = hqB[cur][kh * 32 + (lane & 31)];
    int szA = 0, srA = 0, sgA = 0, szB = 0, srB = 0, sgB = 0;
    #pragma unroll
    for (int c = 0; c < 32; ++c) {
      int ha = __builtin_amdgcn_readlane((int)hwA, c);
      int hb = __builtin_amdgcn_readlane((int)hwB, c);
      szA = DOT4(ha, CHUNK(wz, c), szA);
      szB = DOT4(hb, CHUNK(wz, c), szB);
      srA = DOT4(ha, CHUNK(wr, c), srA);
      srB = DOT4(hb, CHUNK(wr, c), srB);
      sgA = DOT4(ha, CHUNK(wg, c), sgA);
      sgB = DOT4(hb, CHUNK(wg, c), sgB);
    }
    // publish the partials of the OTHER batch's gate group
    if (kh) { pubA[0][j] = szA; pubA[1][j] = srA; pubA[2][j] = sgA; }
    else    { pubB[0][j] = szB; pubB[1][j] = srB; pubB[2][j] = sgB; }
    barrier_lds();   // #1: partials visible

    // ---- gates: tid<256 -> batch A (own partial = kh0's A), tid>=256 -> B
    {
      int sz, sr, sg;
      if (kh == 0) { sz = szA + pubA[0][j]; sr = srA + pubA[1][j]; sg = sgA + pubA[2][j]; }
      else         { sz = szB + pubB[0][j]; sr = srB + pubB[1][j]; sg = sgB + pubB[2][j]; }
      int vz = clamp8(rne_half(2 * clamp8(rne_s8(sz)) + vbz));
      int vr = clamp8(rne_half(2 * clamp8(rne_s8(sr)) + vbr));
      int vg = clamp8(rne_half(2 * clamp8(rne_s8(sg)) + vbg));
      int az = clamp8(rne_half(2 * (wxA0 + vz) + bzc));
      int zi = (int)lutS[az + 128];
      int ar = clamp8(rne_half(2 * (wxA1 + vr) + brc));
      int ri = (int)lutS[ar + 128];
      int rrh = clamp8(rne_s7(ri * vg));
      int ag = clamp8(rne_half(2 * (wxA2 + rrh) + bgc));
      int gi = (int)lutT[ag + 128];
      int oldi = clamp8(rne_s7(zi * hi));
      int newi = clamp8(rne_s7((128 - zi) * gi));
      hi = oldi + newi;                       // integer, units 1/128
      outp[(size_t)t * BATCH * HDIM] = (float)hi * (1.0f / 128.0f);
      if (kh == 0) ((int8_t*)&hqA[nxt][0])[j] = (int8_t)clamp8(hi);
      else         ((int8_t*)&hqB[nxt][0])[j] = (int8_t)clamp8(hi);
      wxA0 = wxB0; wxA1 = wxB1; wxA2 = wxB2;
      wxB0 = nz;   wxB1 = nr;   wxB2 = ng;
    }
    barrier_lds();   // #2: hq[nxt] published
  }
}

// ---------------------------------------------------------------------------
extern "C" void kernel_launch(void* const* d_in, const int* in_sizes, int n_in,
                              void* d_out, int out_size, void* d_ws, size_t ws_size,
                              hipStream_t stream) {
  const float* x  = (const float*)d_in[0];   // (T,B,I)
  const float* h0 = (const float*)d_in[1];   // (B,H)
  const float* W  = (const float*)d_in[2];   // (I,3H)
  const float* R  = (const float*)d_in[3];   // (H,3H)
  const float* bx = (const float*)d_in[4];   // (3H,)
  const float* br = (const float*)d_in[5];   // (3H,)
  float* out = (float*)d_out;                // (T,B,H)

  // workspace layout
  const size_t NW = (size_t)IDIM * N3H;          // 196608
  int8_t* Wq  = (int8_t*)d_ws;                   // 196608
  int8_t* Rq  = Wq + NW;                         // 196608
  int8_t* bx8 = Rq + NW;                         // 768
  int8_t* br8 = bx8 + N3H;                       // 768
  int8_t* WxQ8 = br8 + N3H;                      // 64*512*768 = 25165824

  {
    int total = (int)(2 * NW + 2 * N3H);
    int blocks = (total + 255) / 256;
    prep_kernel<<<blocks, 256, 0, stream>>>(W, R, bx, br, Wq, Rq, bx8, br8);
  }
  gemm_wx_kernel<<<T_STEPS, 768, 0, stream>>>(x, Wq, WxQ8);
  gru_rec17_kernel<<<BATCH / 2, 512, 0, stream>>>(h0, Rq, bx8, br8, WxQ8, out);
}

// Round 19
// 559.631 us; speedup vs baseline: 1.5337x; 1.5337x over previous
//
#include <hip/hip_runtime.h>
#include <hip/hip_bf16.h>
#include <stdint.h>

// ---------------------------------------------------------------------------
// QuantGRU: T=512, B=64, I=256, H=256. ACT scale 2^-7, W scale 2^-8.
// Fully exact integer arithmetic; sigmoid/tanh via 256-entry f64-built LUTs.
// R19: R18 (inline-asm MFMA, B operands AGPR-resident via "a" constraint)
// + the missing MFMA HAZARD GUARDS: s_nop 2 before the chain (VALU zero-init
// -> SrcC), back-to-back same-D accumulation (HW-forwarded), s_nop 7 x2
// after (D -> VALU/LDS-read). R18's absmax 0.59 was exactly these hazards --
// raw asm MFMA gets no compiler-inserted wait states.
// ---------------------------------------------------------------------------

#define T_STEPS 512
#define BATCH   64
#define IDIM    256
#define HDIM    256
#define N3H     768   // 3*H

typedef int v4i __attribute__((ext_vector_type(4)));

#if defined(__has_builtin)
#if __has_builtin(__builtin_amdgcn_sdot4)
#define DOT4(a,b,c) __builtin_amdgcn_sdot4((int)(a),(int)(b),(int)(c),false)
#endif
#endif
#ifndef DOT4
__device__ __forceinline__ int dot4_sw(uint32_t a, uint32_t b, int c){
  c += (int)(int8_t)(a)      * (int)(int8_t)(b);
  c += (int)(int8_t)(a>>8)   * (int)(int8_t)(b>>8);
  c += (int)(int8_t)(a>>16)  * (int)(int8_t)(b>>16);
  c += (int)(int8_t)(a>>24)  * (int)(int8_t)(b>>24);
  return c;
}
#define DOT4(a,b,c) dot4_sw((uint32_t)(a),(uint32_t)(b),(int)(c))
#endif

// 4-deep MFMA accumulation chain, B operands AGPR-resident ("a"), with
// explicit hazard guards (raw asm MFMA gets no compiler wait states):
//   s_nop 2          VALU z-init -> MFMA SrcC
//   same-D chaining  HW-forwarded, no waits (m119 dependent-chain at peak)
//   s_nop 7 x2       MFMA D -> VALU/ds_write read
#define MFMA4_A(z, A0, A1, A2, A3, B0, B1, B2, B3)                    \
  asm volatile("s_nop 2\n\t"                                          \
      "v_mfma_i32_16x16x64_i8 %0, %1, %5, %0\n\t"                     \
      "v_mfma_i32_16x16x64_i8 %0, %2, %6, %0\n\t"                     \
      "v_mfma_i32_16x16x64_i8 %0, %3, %7, %0\n\t"                     \
      "v_mfma_i32_16x16x64_i8 %0, %4, %8, %0\n\t"                     \
      "s_nop 7\n\t"                                                   \
      "s_nop 7"                                                       \
      : "+v"(z)                                                       \
      : "v"(A0), "v"(A1), "v"(A2), "v"(A3),                           \
        "a"(B0), "a"(B1), "a"(B2), "a"(B3))

// LDS-only workgroup barrier (no vmcnt drain; loads/stores stay in flight)
__device__ __forceinline__ void barrier_lds() {
  asm volatile("s_waitcnt lgkmcnt(0)\n\ts_barrier" ::: "memory");
}

// ---- exact integer round-to-nearest-even helpers (verified vs jnp.round) ---
__device__ __forceinline__ int clamp8(int x)   { return min(127, max(-128, x)); }
__device__ __forceinline__ int rne_half(int y) { int t = y >> 1; return t + (t & y & 1); }
__device__ __forceinline__ int rne_s8(int s)   { return (s + 127 + ((s >> 8) & 1)) >> 8; }
__device__ __forceinline__ int rne_s7(int p)   { return (p + 63 + ((p >> 7) & 1)) >> 7; }

// float RNE+clamp (quantize; used in prep/gemm only)
__device__ __forceinline__ int rneclamp(float v) {
  int q = (int)rintf(v);
  return min(127, max(-128, q));
}

__device__ __forceinline__ uint32_t packq4(float4 f, float sc) {
  uint32_t b0 = (uint32_t)(uint8_t)(int8_t)rneclamp(f.x * sc);
  uint32_t b1 = (uint32_t)(uint8_t)(int8_t)rneclamp(f.y * sc);
  uint32_t b2 = (uint32_t)(uint8_t)(int8_t)rneclamp(f.z * sc);
  uint32_t b3 = (uint32_t)(uint8_t)(int8_t)rneclamp(f.w * sc);
  return b0 | (b1 << 8) | (b2 << 16) | (b3 << 24);
}

// ---------------------------------------------------------------------------
// prep: W -> k-chunk-transposed int8 (for gemm_wx), R -> MFMA B-FRAGMENT
// layout: byte (((n*4+s)*64+l)*16+e) = R[k][col]*256, k=s*64+(l>>4)*16+e,
// col=n*16+(l&15)  (n=N-tile 0..47, s=K-slice 0..3, l=lane, e=byte).
// ---------------------------------------------------------------------------
__global__ void prep_kernel(const float* __restrict__ W, const float* __restrict__ R,
                            const float* __restrict__ bx, const float* __restrict__ br,
                            int8_t* __restrict__ Wq, int8_t* __restrict__ BF,
                            int8_t* __restrict__ bx8, int8_t* __restrict__ br8) {
  const int NW = IDIM * N3H; // 196608
  int idx = blockIdx.x * 256 + threadIdx.x;
  if (idx < NW) {
    int k = idx / N3H, j = idx % N3H;
    Wq[((size_t)(k >> 4) * N3H + j) * 16 + (k & 15)] = (int8_t)rneclamp(W[idx] * 256.0f);
  } else if (idx < 2 * NW) {
    int i2 = idx - NW;               // linear index into BF
    int e = i2 & 15;
    int l = (i2 >> 4) & 63;
    int s = (i2 >> 10) & 3;
    int n = i2 >> 12;                // 0..47
    int k   = s * 64 + ((l >> 4) << 4) + e;
    int col = n * 16 + (l & 15);
    BF[i2] = (int8_t)rneclamp(R[(size_t)k * N3H + col] * 256.0f);
  } else if (idx < 2 * NW + N3H) {
    int i2 = idx - 2 * NW;
    bx8[i2] = (int8_t)rneclamp(bx[i2] * 256.0f);
  } else if (idx < 2 * NW + 2 * N3H) {
    int i2 = idx - 2 * NW - N3H;
    br8[i2] = (int8_t)rneclamp(br[i2] * 256.0f);
  }
}

// ---------------------------------------------------------------------------
// gemm_wx: Wx_q[b][t][j] = clamp(rne( (fq(x) . Wq col j) / 256 ))  (int8)
// one block per t (64 rows), 768 threads = one per output column.
// ---------------------------------------------------------------------------
__global__ __launch_bounds__(768, 1) void gemm_wx_kernel(
    const float* __restrict__ x, const int8_t* __restrict__ Wq,
    int8_t* __restrict__ WxQ8) {
  const int t = blockIdx.x;   // 0..511
  const int j = threadIdx.x;  // 0..767

  __shared__ uint4 xq4[64 * 16];   // 64 rows x 256 int8 = 16KB
  uint32_t* xq = (uint32_t*)xq4;

  uint4 w[16];
  const uint4* wp = (const uint4*)Wq;
  #pragma unroll
  for (int kk = 0; kk < 16; ++kk) w[kk] = wp[kk * N3H + j];

  const float4* xg = (const float4*)(x) + (size_t)t * 4096;
  for (int i = j; i < 4096; i += 768) {
    float4 f = xg[i];
    xq[i] = packq4(f, 128.0f);
  }
  __syncthreads();

  for (int r = 0; r < 64; ++r) {
    int s = 0;
    #pragma unroll
    for (int kk = 0; kk < 16; ++kk) {
      uint4 hv = xq4[r * 16 + kk];
      s = DOT4(hv.x, w[kk].x, s);
      s = DOT4(hv.y, w[kk].y, s);
      s = DOT4(hv.z, w[kk].z, s);
      s = DOT4(hv.w, w[kk].w, s);
    }
    int q = clamp8(rne_s8(s));
    WxQ8[((size_t)r * T_STEPS + t) * N3H + j] = (int8_t)q;
  }
}

// ---------------------------------------------------------------------------
// gru_rec19: one block per batch; 512 threads = 8 waves.
// All waves: MFMA S = hq @ R (6 N-tiles each), B operands AGPR-resident via
// inline-asm "a" constraint (hazard-guarded). Threads 0-255: exact gate tail.
// ---------------------------------------------------------------------------
__global__ __launch_bounds__(512, 1)
void gru_rec19_kernel(
    const float* __restrict__ h0, const int8_t* __restrict__ BF,
    const int8_t* __restrict__ bx8, const int8_t* __restrict__ br8,
    const int8_t* __restrict__ WxQ8, float* __restrict__ out) {
  const int b    = blockIdx.x;      // batch element
  const int tid  = threadIdx.x;     // 0..511
  const int lane = tid & 63;
  const int wave = tid >> 6;        // 0..7
  const int j    = tid & 255;       // gate index (tid<256)

  __shared__ alignas(16) int8_t hq[2][256];   // int8 h (row 0 of A)
  __shared__ int    Sbuf[N3H];                // raw i32 GEMV results
  __shared__ int8_t lutS[256];
  __shared__ int8_t lutT[256];

  // B fragments: 6 N-tiles x 4 K-slices -> consumed ONLY as "a" asm inputs
  // => allocator keeps all 96 dwords AGPR-resident across the t-loop.
  v4i bf[6][4];
  {
    const v4i* bp = (const v4i*)BF;
    #pragma unroll
    for (int i = 0; i < 6; ++i)
      #pragma unroll
      for (int s = 0; s < 4; ++s)
        bf[i][s] = bp[((wave * 6 + i) * 4 + s) * 64 + lane];
  }

  // gate-thread state (tid < 256)
  int hi = 0, bzc = 0, brc = 0, bgc = 0, vbz = 0, vbr = 0, vbg = 0;
  const int8_t* wxp = WxQ8 + (size_t)b * T_STEPS * N3H + j;
  int wxA0 = 0, wxA1 = 0, wxA2 = 0, wxB0 = 0, wxB1 = 0, wxB2 = 0;
  if (tid < 256) {
    double a = ((double)j - 128.0) / 128.0;
    lutS[j] = (int8_t)min(127, max(-128, (int)rint(128.0 / (1.0 + exp(-a)))));
    lutT[j] = (int8_t)min(127, max(-128, (int)rint(128.0 * tanh(a))));
    bzc = (int)bx8[j];
    brc = (int)bx8[j + 256];
    bgc = (int)bx8[j + 512];
    vbz = (int)br8[j];
    vbr = (int)br8[j + 256];
    vbg = (int)br8[j + 512];
    hi = (int)rintf(h0[b * HDIM + j] * 128.0f);   // exact int, units 1/128
    hq[0][j] = (int8_t)clamp8(hi);
    wxA0 = (int)wxp[0];   wxA1 = (int)wxp[256];       wxA2 = (int)wxp[512];
    wxB0 = (int)wxp[N3H]; wxB1 = (int)wxp[N3H + 256]; wxB2 = (int)wxp[N3H + 512];
  }
  __syncthreads();

  float* outp = out + (size_t)b * HDIM + j;
  const int kg = (lane >> 4) << 4;   // 0,16,32,48 within each 64-wide K-slice

  for (int t = 0; t < T_STEPS; ++t) {
    const int cur = t & 1, nxt = cur ^ 1;

    // issue Wx loads for t+2 (gate threads)
    int nz = 0, nr = 0, ng = 0;
    if (tid < 256) {
      const int8_t* p = wxp + (size_t)min(t + 2, T_STEPS - 1) * N3H;
      nz = (int)p[0]; nr = (int)p[256]; ng = (int)p[512];
    }

    // ---- A fragments from hq row (rows 1-15 of A are duplicates; harmless)
    v4i a0 = *(const v4i*)&hq[cur][  0 + kg];
    v4i a1 = *(const v4i*)&hq[cur][ 64 + kg];
    v4i a2 = *(const v4i*)&hq[cur][128 + kg];
    v4i a3 = *(const v4i*)&hq[cur][192 + kg];

    // ---- MFMA: 6 tiles x 4 K-slices, B read directly from AGPRs
    v4i acc[6];
    #pragma unroll
    for (int i = 0; i < 6; ++i) {
      v4i z = {0, 0, 0, 0};
      MFMA4_A(z, a0, a1, a2, a3, bf[i][0], bf[i][1], bf[i][2], bf[i][3]);
      acc[i] = z;
    }
    // ---- extract row 0: col=lane&15, row=(lane>>4)*4+reg => lanes 0-15, reg 0
    if (lane < 16) {
      #pragma unroll
      for (int i = 0; i < 6; ++i)
        Sbuf[(wave * 6 + i) * 16 + lane] = acc[i][0];
    }
    barrier_lds();   // #1: Sbuf ready

    // ---- gate tail (threads 0-255), exact integer (verbatim R6) ----
    if (tid < 256) {
      int sz = Sbuf[j], sr = Sbuf[j + 256], sg = Sbuf[j + 512];
      int vz = clamp8(rne_half(2 * clamp8(rne_s8(sz)) + vbz));
      int vr = clamp8(rne_half(2 * clamp8(rne_s8(sr)) + vbr));
      int vg = clamp8(rne_half(2 * clamp8(rne_s8(sg)) + vbg));
      int az = clamp8(rne_half(2 * (wxA0 + vz) + bzc));
      int zi = (int)lutS[az + 128];
      int ar = clamp8(rne_half(2 * (wxA1 + vr) + brc));
      int ri = (int)lutS[ar + 128];
      int rrh = clamp8(rne_s7(ri * vg));
      int ag = clamp8(rne_half(2 * (wxA2 + rrh) + bgc));
      int gi = (int)lutT[ag + 128];
      int oldi = clamp8(rne_s7(zi * hi));
      int newi = clamp8(rne_s7((128 - zi) * gi));
      hi = oldi + newi;                       // integer, units 1/128
      outp[(size_t)t * BATCH * HDIM] = (float)hi * (1.0f / 128.0f);
      hq[nxt][j] = (int8_t)clamp8(hi);
      wxA0 = wxB0; wxA1 = wxB1; wxA2 = wxB2;
      wxB0 = nz;   wxB1 = nr;   wxB2 = ng;
    }
    barrier_lds();   // #2: hq[nxt] published
  }
}

// ---------------------------------------------------------------------------
extern "C" void kernel_launch(void* const* d_in, const int* in_sizes, int n_in,
                              void* d_out, int out_size, void* d_ws, size_t ws_size,
                              hipStream_t stream) {
  const float* x  = (const float*)d_in[0];   // (T,B,I)
  const float* h0 = (const float*)d_in[1];   // (B,H)
  const float* W  = (const float*)d_in[2];   // (I,3H)
  const float* R  = (const float*)d_in[3];   // (H,3H)
  const float* bx = (const float*)d_in[4];   // (3H,)
  const float* br = (const float*)d_in[5];   // (3H,)
  float* out = (float*)d_out;                // (T,B,H)

  // workspace layout
  const size_t NW = (size_t)IDIM * N3H;          // 196608
  int8_t* Wq  = (int8_t*)d_ws;                   // 196608
  int8_t* BF  = Wq + NW;                         // 196608 (R as MFMA B-frags)
  int8_t* bx8 = BF + NW;                         // 768
  int8_t* br8 = bx8 + N3H;                       // 768
  int8_t* WxQ8 = br8 + N3H;                      // 64*512*768 = 25165824

  {
    int total = (int)(2 * NW + 2 * N3H);
    int blocks = (total + 255) / 256;
    prep_kernel<<<blocks, 256, 0, stream>>>(W, R, bx, br, Wq, BF, bx8, br8);
  }
  gemm_wx_kernel<<<T_STEPS, 768, 0, stream>>>(x, Wq, WxQ8);
  gru_rec19_kernel<<<BATCH, 512, 0, stream>>>(h0, BF, bx8, br8, WxQ8, out);
}

// Round 20
// 471.844 us; speedup vs baseline: 1.8190x; 1.1861x over previous
//
#include <hip/hip_runtime.h>
#include <hip/hip_bf16.h>
#include <stdint.h>

// ---------------------------------------------------------------------------
// QuantGRU: T=512, B=64, I=256, H=256. ACT scale 2^-7, W scale 2^-8.
// Fully exact integer arithmetic; gate nonlinearities via LDS LUTs built in
// f64 (exact compositions of the integer ops -- bit-identical to reference).
// R20 = R12 (best, 394us) + DEPENDENCY-CHAIN SHORTENING:
//  - 4-way split dot4 accumulators (chain depth 64 -> 16 dependent ops;
//    the 64-deep serial accumulate was ~400-500 cyc/step of latency stall)
//  - lutRR (64KB) dropped: rrh via lutS gather + 4 VALU ops (same critical
//    gather depth, frees LDS + its conflicts). lutS2/lutT2 fused LUTs kept.
// ---------------------------------------------------------------------------

#define T_STEPS 512
#define BATCH   64
#define IDIM    256
#define HDIM    256
#define N3H     768   // 3*H

#if defined(__has_builtin)
#if __has_builtin(__builtin_amdgcn_sdot4)
#define DOT4(a,b,c) __builtin_amdgcn_sdot4((int)(a),(int)(b),(int)(c),false)
#endif
#endif
#ifndef DOT4
__device__ __forceinline__ int dot4_sw(uint32_t a, uint32_t b, int c){
  c += (int)(int8_t)(a)      * (int)(int8_t)(b);
  c += (int)(int8_t)(a>>8)   * (int)(int8_t)(b>>8);
  c += (int)(int8_t)(a>>16)  * (int)(int8_t)(b>>16);
  c += (int)(int8_t)(a>>24)  * (int)(int8_t)(b>>24);
  return c;
}
#define DOT4(a,b,c) dot4_sw((uint32_t)(a),(uint32_t)(b),(int)(c))
#endif

// LDS-only workgroup barrier (no vmcnt drain; loads/stores stay in flight)
__device__ __forceinline__ void barrier_lds() {
  asm volatile("s_waitcnt lgkmcnt(0)\n\ts_barrier" ::: "memory");
}

// ---- exact integer round-to-nearest-even helpers (verified vs jnp.round) ---
__device__ __forceinline__ int clamp8(int x)   { return min(127, max(-128, x)); }
__device__ __forceinline__ int rne_half(int y) { int t = y >> 1; return t + (t & y & 1); }
__device__ __forceinline__ int rne_s8(int s)   { return (s + 127 + ((s >> 8) & 1)) >> 8; }
__device__ __forceinline__ int rne_s7(int p)   { return (p + 63 + ((p >> 7) & 1)) >> 7; }

// float RNE+clamp (quantize; used in prep/gemm only)
__device__ __forceinline__ int rneclamp(float v) {
  int q = (int)rintf(v);
  return min(127, max(-128, q));
}

__device__ __forceinline__ uint32_t packq4(float4 f, float sc) {
  uint32_t b0 = (uint32_t)(uint8_t)(int8_t)rneclamp(f.x * sc);
  uint32_t b1 = (uint32_t)(uint8_t)(int8_t)rneclamp(f.y * sc);
  uint32_t b2 = (uint32_t)(uint8_t)(int8_t)rneclamp(f.z * sc);
  uint32_t b3 = (uint32_t)(uint8_t)(int8_t)rneclamp(f.w * sc);
  return b0 | (b1 << 8) | (b2 << 16) | (b3 << 24);
}

// ---------------------------------------------------------------------------
// prep: W -> k-chunk-transposed int8 (for gemm_wx coalesced column loads),
// R -> plain column-major int8, biases -> int8.
// ---------------------------------------------------------------------------
__global__ void prep_kernel(const float* __restrict__ W, const float* __restrict__ R,
                            const float* __restrict__ bx, const float* __restrict__ br,
                            int8_t* __restrict__ Wq, int8_t* __restrict__ Rq,
                            int8_t* __restrict__ bx8, int8_t* __restrict__ br8) {
  const int NW = IDIM * N3H; // 196608
  int idx = blockIdx.x * 256 + threadIdx.x;
  if (idx < NW) {
    int k = idx / N3H, j = idx % N3H;
    Wq[((size_t)(k >> 4) * N3H + j) * 16 + (k & 15)] = (int8_t)rneclamp(W[idx] * 256.0f);
  } else if (idx < 2 * NW) {
    int i2 = idx - NW;
    int k = i2 / N3H, j = i2 % N3H;
    Rq[(size_t)j * HDIM + k] = (int8_t)rneclamp(R[i2] * 256.0f);   // col-major
  } else if (idx < 2 * NW + N3H) {
    int i2 = idx - 2 * NW;
    bx8[i2] = (int8_t)rneclamp(bx[i2] * 256.0f);
  } else if (idx < 2 * NW + 2 * N3H) {
    int i2 = idx - 2 * NW - N3H;
    br8[i2] = (int8_t)rneclamp(br[i2] * 256.0f);
  }
}

// ---------------------------------------------------------------------------
// gemm_wx: Wx_q[b][t][j] = clamp(rne( (fq(x) . Wq col j) / 256 ))  (int8)
// one block per t (64 rows), 768 threads = one per output column.
// ---------------------------------------------------------------------------
__global__ __launch_bounds__(768, 1) void gemm_wx_kernel(
    const float* __restrict__ x, const int8_t* __restrict__ Wq,
    int8_t* __restrict__ WxQ8) {
  const int t = blockIdx.x;   // 0..511
  const int j = threadIdx.x;  // 0..767

  __shared__ uint4 xq4[64 * 16];   // 64 rows x 256 int8 = 16KB
  uint32_t* xq = (uint32_t*)xq4;

  uint4 w[16];
  const uint4* wp = (const uint4*)Wq;
  #pragma unroll
  for (int kk = 0; kk < 16; ++kk) w[kk] = wp[kk * N3H + j];

  const float4* xg = (const float4*)(x) + (size_t)t * 4096;
  for (int i = j; i < 4096; i += 768) {
    float4 f = xg[i];
    xq[i] = packq4(f, 128.0f);
  }
  __syncthreads();

  for (int r = 0; r < 64; ++r) {
    int s0 = 0, s1 = 0, s2 = 0, s3 = 0;
    #pragma unroll
    for (int kk = 0; kk < 4; ++kk) {
      uint4 hv = xq4[r * 16 + kk];
      s0 = DOT4(hv.x, w[kk].x, s0);
      s0 = DOT4(hv.y, w[kk].y, s0);
      s0 = DOT4(hv.z, w[kk].z, s0);
      s0 = DOT4(hv.w, w[kk].w, s0);
      uint4 h1 = xq4[r * 16 + 4 + kk];
      s1 = DOT4(h1.x, w[4 + kk].x, s1);
      s1 = DOT4(h1.y, w[4 + kk].y, s1);
      s1 = DOT4(h1.z, w[4 + kk].z, s1);
      s1 = DOT4(h1.w, w[4 + kk].w, s1);
      uint4 h2 = xq4[r * 16 + 8 + kk];
      s2 = DOT4(h2.x, w[8 + kk].x, s2);
      s2 = DOT4(h2.y, w[8 + kk].y, s2);
      s2 = DOT4(h2.z, w[8 + kk].z, s2);
      s2 = DOT4(h2.w, w[8 + kk].w, s2);
      uint4 h3 = xq4[r * 16 + 12 + kk];
      s3 = DOT4(h3.x, w[12 + kk].x, s3);
      s3 = DOT4(h3.y, w[12 + kk].y, s3);
      s3 = DOT4(h3.z, w[12 + kk].z, s3);
      s3 = DOT4(h3.w, w[12 + kk].w, s3);
    }
    int s = (s0 + s1) + (s2 + s3);
    int q = clamp8(rne_s8(s));
    WxQ8[((size_t)r * T_STEPS + t) * N3H + j] = (int8_t)q;
  }
}

// ---------------------------------------------------------------------------
// gru_rec20: one block per batch; 256 threads (4 waves), thread j owns h[j]
// and its gate triple. Static LDS (~5KB):
//   lutS2[2048]: zi  = f(2*(wz+vz)+bz)   (index-fused sigmoid)
//   lutT2[2048]: gi  = f(2*(wg+rrh)+bg)  (index-fused tanh)
//   lutS [256] : ri  = sigmoid-quant     (for the rrh VALU path)
//   hq[2][16]  : double-buffered int8 h
// GEMV: h via wave-uniform ds_read_b128 broadcasts; dot4 with 4-WAY SPLIT
// accumulators (dependency chain 64 -> 16).
// ---------------------------------------------------------------------------
__global__ __launch_bounds__(256, 1)
void gru_rec20_kernel(
    const float* __restrict__ h0, const int8_t* __restrict__ Rq,
    const int8_t* __restrict__ bx8, const int8_t* __restrict__ br8,
    const int8_t* __restrict__ WxQ8, float* __restrict__ out) {
  const int b = blockIdx.x;     // batch element
  const int j = threadIdx.x;    // 0..255

  __shared__ int8_t lutS2[2048];
  __shared__ int8_t lutT2[2048];
  __shared__ int8_t lutS[256];
  __shared__ alignas(16) uint4 hqb[2][16];

  // R columns j, j+256, j+512
  uint4 wz[16], wr[16], wg[16];
  {
    const uint4* pz = (const uint4*)(Rq + (size_t)j * HDIM);
    const uint4* pr = (const uint4*)(Rq + (size_t)(j + 256) * HDIM);
    const uint4* pg = (const uint4*)(Rq + (size_t)(j + 512) * HDIM);
    #pragma unroll
    for (int kk = 0; kk < 16; ++kk) { wz[kk] = pz[kk]; wr[kk] = pr[kk]; wg[kk] = pg[kk]; }
  }
  const int bzc = (int)bx8[j];
  const int brc = (int)bx8[j + 256];
  const int bgc = (int)bx8[j + 512];
  const int vbz = (int)br8[j];
  const int vbr = (int)br8[j + 256];
  const int vbg = (int)br8[j + 512];

  // ---- build LUTs in f64 (exact compositions of the integer ops) ----
  {
    const double inv128 = 1.0 / 128.0;
    #pragma unroll
    for (int i = 0; i < 8; ++i) {
      int y = j * 8 + i - 1024;
      int v = clamp8(rne_half(y));
      lutS2[j * 8 + i] = (int8_t)clamp8((int)rint(128.0 / (1.0 + exp(-(double)v * inv128))));
      lutT2[j * 8 + i] = (int8_t)clamp8((int)rint(128.0 * tanh((double)v * inv128)));
    }
    double a = ((double)j - 128.0) * inv128;
    lutS[j] = (int8_t)clamp8((int)rint(128.0 / (1.0 + exp(-a))));
  }
  // h carried as exact integer hi (units 1/128)
  int hi = (int)rintf(h0[b * HDIM + j] * 128.0f);
  ((int8_t*)&hqb[0][0])[j] = (int8_t)clamp8(hi);
  __syncthreads();

  const int8_t* wxp = WxQ8 + (size_t)b * T_STEPS * N3H + j;
  float* outp = out + (size_t)b * HDIM + j;

  // Wx 2-deep prefetch pipeline: A = step t, B = step t+1
  int wxA0 = (int)wxp[0],   wxA1 = (int)wxp[256],       wxA2 = (int)wxp[512];
  int wxB0 = (int)wxp[N3H], wxB1 = (int)wxp[N3H + 256], wxB2 = (int)wxp[N3H + 512];

  for (int t = 0; t < T_STEPS; ++t) {
    const int cur = t & 1, nxt = cur ^ 1;

    // issue Wx loads for t+2 first (~2 steps of latency hiding)
    const int8_t* p = wxp + (size_t)min(t + 2, T_STEPS - 1) * N3H;
    int nz = (int)p[0], nr = (int)p[256], ng = (int)p[512];

    // ---- GEMV: h via wave-uniform ds_read_b128; 4-way split accumulators
    const uint4* hc = &hqb[cur][0];
    int sz0 = 0, sz1 = 0, sz2 = 0, sz3 = 0;
    int sr0 = 0, sr1 = 0, sr2 = 0, sr3 = 0;
    int sg0 = 0, sg1 = 0, sg2 = 0, sg3 = 0;
    #pragma unroll
    for (int kk = 0; kk < 4; ++kk) {
      uint4 h0v = hc[kk];
      sz0 = DOT4(h0v.x, wz[kk].x, sz0);  sz0 = DOT4(h0v.y, wz[kk].y, sz0);
      sz0 = DOT4(h0v.z, wz[kk].z, sz0);  sz0 = DOT4(h0v.w, wz[kk].w, sz0);
      sr0 = DOT4(h0v.x, wr[kk].x, sr0);  sr0 = DOT4(h0v.y, wr[kk].y, sr0);
      sr0 = DOT4(h0v.z, wr[kk].z, sr0);  sr0 = DOT4(h0v.w, wr[kk].w, sr0);
      sg0 = DOT4(h0v.x, wg[kk].x, sg0);  sg0 = DOT4(h0v.y, wg[kk].y, sg0);
      sg0 = DOT4(h0v.z, wg[kk].z, sg0);  sg0 = DOT4(h0v.w, wg[kk].w, sg0);
      uint4 h1v = hc[4 + kk];
      sz1 = DOT4(h1v.x, wz[4 + kk].x, sz1);  sz1 = DOT4(h1v.y, wz[4 + kk].y, sz1);
      sz1 = DOT4(h1v.z, wz[4 + kk].z, sz1);  sz1 = DOT4(h1v.w, wz[4 + kk].w, sz1);
      sr1 = DOT4(h1v.x, wr[4 + kk].x, sr1);  sr1 = DOT4(h1v.y, wr[4 + kk].y, sr1);
      sr1 = DOT4(h1v.z, wr[4 + kk].z, sr1);  sr1 = DOT4(h1v.w, wr[4 + kk].w, sr1);
      sg1 = DOT4(h1v.x, wg[4 + kk].x, sg1);  sg1 = DOT4(h1v.y, wg[4 + kk].y, sg1);
      sg1 = DOT4(h1v.z, wg[4 + kk].z, sg1);  sg1 = DOT4(h1v.w, wg[4 + kk].w, sg1);
      uint4 h2v = hc[8 + kk];
      sz2 = DOT4(h2v.x, wz[8 + kk].x, sz2);  sz2 = DOT4(h2v.y, wz[8 + kk].y, sz2);
      sz2 = DOT4(h2v.z, wz[8 + kk].z, sz2);  sz2 = DOT4(h2v.w, wz[8 + kk].w, sz2);
      sr2 = DOT4(h2v.x, wr[8 + kk].x, sr2);  sr2 = DOT4(h2v.y, wr[8 + kk].y, sr2);
      sr2 = DOT4(h2v.z, wr[8 + kk].z, sr2);  sr2 = DOT4(h2v.w, wr[8 + kk].w, sr2);
      sg2 = DOT4(h2v.x, wg[8 + kk].x, sg2);  sg2 = DOT4(h2v.y, wg[8 + kk].y, sg2);
      sg2 = DOT4(h2v.z, wg[8 + kk].z, sg2);  sg2 = DOT4(h2v.w, wg[8 + kk].w, sg2);
      uint4 h3v = hc[12 + kk];
      sz3 = DOT4(h3v.x, wz[12 + kk].x, sz3);  sz3 = DOT4(h3v.y, wz[12 + kk].y, sz3);
      sz3 = DOT4(h3v.z, wz[12 + kk].z, sz3);  sz3 = DOT4(h3v.w, wz[12 + kk].w, sz3);
      sr3 = DOT4(h3v.x, wr[12 + kk].x, sr3);  sr3 = DOT4(h3v.y, wr[12 + kk].y, sr3);
      sr3 = DOT4(h3v.z, wr[12 + kk].z, sr3);  sr3 = DOT4(h3v.w, wr[12 + kk].w, sr3);
      sg3 = DOT4(h3v.x, wg[12 + kk].x, sg3);  sg3 = DOT4(h3v.y, wg[12 + kk].y, sg3);
      sg3 = DOT4(h3v.z, wg[12 + kk].z, sg3);  sg3 = DOT4(h3v.w, wg[12 + kk].w, sg3);
    }
    int sz = (sz0 + sz1) + (sz2 + sz3);
    int sr = (sr0 + sr1) + (sr2 + sr3);
    int sg = (sg0 + sg1) + (sg2 + sg3);

    // v = fq(fq(s/2^15,7)+br,7)  -- all integer, exact
    int vz = clamp8(rne_half(2 * clamp8(rne_s8(sz)) + vbz));
    int vr = clamp8(rne_half(2 * clamp8(rne_s8(sr)) + vbr));
    int vg = clamp8(rne_half(2 * clamp8(rne_s8(sg)) + vbg));

    // gates: zi via fused lutS2 (off critical path); critical = r-chain
    int zi  = (int)lutS2[2 * (wxA0 + vz) + bzc + 1024];
    int ar  = clamp8(rne_half(2 * (wxA1 + vr) + brc));
    int ri  = (int)lutS[ar + 128];
    int rrh = clamp8(rne_s7(ri * vg));
    int gi  = (int)lutT2[2 * (wxA2 + rrh) + bgc + 1024];
    int oldi = clamp8(rne_s7(zi * hi));
    int newi = clamp8(rne_s7((128 - zi) * gi));
    hi = oldi + newi;                       // integer, units 1/128
    outp[(size_t)t * BATCH * HDIM] = (float)hi * (1.0f / 128.0f);
    ((int8_t*)&hqb[nxt][0])[j] = (int8_t)clamp8(hi);

    // advance Wx pipeline
    wxA0 = wxB0; wxA1 = wxB1; wxA2 = wxB2;
    wxB0 = nz;   wxB1 = nr;   wxB2 = ng;

    barrier_lds();   // LDS-only: hq[nxt] visible; vmcnt stays in flight
  }
}

// ---------------------------------------------------------------------------
extern "C" void kernel_launch(void* const* d_in, const int* in_sizes, int n_in,
                              void* d_out, int out_size, void* d_ws, size_t ws_size,
                              hipStream_t stream) {
  const float* x  = (const float*)d_in[0];   // (T,B,I)
  const float* h0 = (const float*)d_in[1];   // (B,H)
  const float* W  = (const float*)d_in[2];   // (I,3H)
  const float* R  = (const float*)d_in[3];   // (H,3H)
  const float* bx = (const float*)d_in[4];   // (3H,)
  const float* br = (const float*)d_in[5];   // (3H,)
  float* out = (float*)d_out;                // (T,B,H)

  // workspace layout
  const size_t NW = (size_t)IDIM * N3H;          // 196608
  int8_t* Wq  = (int8_t*)d_ws;                   // 196608
  int8_t* Rq  = Wq + NW;                         // 196608
  int8_t* bx8 = Rq + NW;                         // 768
  int8_t* br8 = bx8 + N3H;                       // 768
  int8_t* WxQ8 = br8 + N3H;                      // 64*512*768 = 25165824

  {
    int total = (int)(2 * NW + 2 * N3H);
    int blocks = (total + 255) / 256;
    prep_kernel<<<blocks, 256, 0, stream>>>(W, R, bx, br, Wq, Rq, bx8, br8);
  }
  gemm_wx_kernel<<<T_STEPS, 768, 0, stream>>>(x, Wq, WxQ8);
  gru_rec20_kernel<<<BATCH, 256, 0, stream>>>(h0, Rq, bx8, br8, WxQ8, out);
}